// Round 4
// baseline (137.393 us; speedup 1.0000x reference)
//
#include <hip/hip_runtime.h>
#include <hip/hip_bf16.h>

#define B_SZ 128
#define IN_CAPS 1152
#define N_CAPS 16
#define DIM 16

#define IPB 8                         // i's per (ic,bt) hat block
#define ICN (IN_CAPS / IPB)           // 144 partial slices
#define OUT_ELEMS (B_SZ * N_CAPS * DIM)   // 32768
#define HAT_BLK_U2 8192               // uint2 per (ic,bt) block (32768 shorts)

typedef __attribute__((ext_vector_type(8))) short bf16x8;   // MFMA A/B frag
typedef __attribute__((ext_vector_type(4))) float f32x4;    // MFMA C/D frag

__device__ __forceinline__ unsigned short f2bf(float f) {   // RNE
    unsigned u = __float_as_uint(f);
    u = u + 0x7fffu + ((u >> 16) & 1u);
    return (unsigned short)(u >> 16);
}
__device__ __forceinline__ unsigned pk2(float lo, float hi) {
    return ((unsigned)f2bf(hi) << 16) | f2bf(lo);
}
__device__ __forceinline__ unsigned cvtpk(float lo, float hi) {   // HW packed cvt (RNE)
    union { __hip_bfloat162 h; unsigned u; } c;
    c.h = __float22bfloat162_rn(make_float2(lo, hi));
    return c.u;
}

// DPP sums (VALU pipe — no DS traffic)
__device__ __forceinline__ float dpp_sum16(float v) {
    v += __int_as_float(__builtin_amdgcn_update_dpp(0, __float_as_int(v), 0xB1, 0xF, 0xF, true));
    v += __int_as_float(__builtin_amdgcn_update_dpp(0, __float_as_int(v), 0x4E, 0xF, 0xF, true));
    v += __int_as_float(__builtin_amdgcn_update_dpp(0, __float_as_int(v), 0x124, 0xF, 0xF, true));
    v += __int_as_float(__builtin_amdgcn_update_dpp(0, __float_as_int(v), 0x128, 0xF, 0xF, true));
    return v;
}
__device__ __forceinline__ float dpp_sum8(float v) {
    v += __int_as_float(__builtin_amdgcn_update_dpp(0, __float_as_int(v), 0xB1, 0xF, 0xF, true));
    v += __int_as_float(__builtin_amdgcn_update_dpp(0, __float_as_int(v), 0x4E, 0xF, 0xF, true));
    v += __int_as_float(__builtin_amdgcn_update_dpp(0, __float_as_int(v), 0x141, 0xF, 0xF, true));
    return v;
}

// XCD-aware decode for pass_r (1152 blocks): all 8 bt of an ic share one XCD.
__device__ __forceinline__ void decode_blk(int id, int& ic, int& bt) {
    const int xcd = id & 7, j = id >> 3;   // j in [0,144)
    ic = xcd * 18 + (j >> 3);
    bt = j & 7;
}

// ---- hat materialization: one block per (i, bt). 9216 blocks, no chunk
// loop, no partial accumulation -> short load->MFMA->store burst, write-
// throughput bound. XCD decode keeps all 8 bt of an i on one XCD (W reuse).
// Layout (unchanged): uint2 idx in (ic,bt) block = ch*1024 + w*256 + lane*4 + np. ----
__global__ __launch_bounds__(256)
void hat_mat(const float* __restrict__ x, const float* __restrict__ W,
             unsigned short* __restrict__ hat)
{
    const int tid  = threadIdx.x;
    const int lane = tid & 63;
    const int w    = tid >> 6;
    const int em   = lane & 15;       // D col = b (B operand = x)
    const int q    = lane >> 4;       // D rows = e = 4q+r
    const int id   = blockIdx.x;
    const int j    = id >> 3;
    const int i    = (id & 7) * 144 + (j >> 3);   // i in [0,1152)
    const int bt   = j & 7;
    const int ic   = i >> 3, ch = i & 7;

    // B operand: x[b=em][i][0..7] -> bf16, k>=8 zeroed (kills A garbage)
    uint4 xu = {0u, 0u, 0u, 0u};
    if (q == 0) {
        const float4* xp = (const float4*)(x + ((size_t)(bt * 16 + em) * IN_CAPS + i) * 8);
        float4 a = xp[0], c = xp[1];
        xu.x = cvtpk(a.x, a.y); xu.y = cvtpk(a.z, a.w);
        xu.z = cvtpk(c.x, c.y); xu.w = cvtpk(c.z, c.w);
    }
    union { uint4 u; bf16x8 v; } bx; bx.u = xu;

    uint2 o[4];
    #pragma unroll
    for (int np = 0; np < 4; ++np) {
        const int nn = 4 * w + np;
        const float4* wp = (const float4*)(W + (((size_t)nn * IN_CAPS + i) * DIM + em) * 8);
        float4 wa = wp[0], wb2 = wp[1];
        union { uint4 u; bf16x8 v; } ax;
        ax.u.x = cvtpk(wa.x, wa.y);   ax.u.y = cvtpk(wa.z, wa.w);
        ax.u.z = cvtpk(wb2.x, wb2.y); ax.u.w = cvtpk(wb2.z, wb2.w);
        f32x4 cz = {0.f, 0.f, 0.f, 0.f};
        f32x4 d = __builtin_amdgcn_mfma_f32_16x16x32_bf16(ax.v, bx.v, cz, 0, 0, 0);
        o[np] = (uint2){cvtpk(d[0], d[1]), cvtpk(d[2], d[3])};  // e 4q..4q+3
    }
    uint2* hw = (uint2*)hat + (size_t)(ic * 8 + bt) * HAT_BLK_U2
              + ch * 1024 + w * 256 + lane * 4;
    uint4 s0 = {o[0].x, o[0].y, o[1].x, o[1].y};
    uint4 s1 = {o[2].x, o[2].y, o[3].x, o[3].y};
    *(uint4*)hw       = s0;   // lane-contiguous 32 B
    *(uint4*)(hw + 2) = s1;
}

// ---- reduce0: accA[b][n][e] = (1/16) * sum_i hat[b,n,i,e], reading hat
// directly (per-i partial IS hat/16). Thread owns one uint2-quad (4 e's),
// sums 288 coalesced terms; LDS combine over grp; un-permute on write. ----
__global__ __launch_bounds__(256)
void reduce0(const uint2* __restrict__ hat2, float2* __restrict__ acc)
{
    const int tid  = threadIdx.x;
    const int ps   = tid & 63;
    const int grp  = tid >> 6;
    const int pos4 = blockIdx.x * 64 + ps;     // [0, 8192) u2 index space
    const int bt   = pos4 >> 10;
    const int inner = pos4 & 1023;             // w*256 + lane*4 + np
    const uint2* hp = hat2 + (size_t)bt * HAT_BLK_U2 + inner;

    float t0 = 0.f, t1 = 0.f, t2 = 0.f, t3 = 0.f;
    for (int icx = grp * 36; icx < grp * 36 + 36; ++icx) {
        #pragma unroll
        for (int chh = 0; chh < 8; ++chh) {
            uint2 u = hp[(size_t)icx * (8 * HAT_BLK_U2) + chh * 1024];
            t0 += __uint_as_float(u.x << 16);
            t1 += __uint_as_float(u.x & 0xFFFF0000u);
            t2 += __uint_as_float(u.y << 16);
            t3 += __uint_as_float(u.y & 0xFFFF0000u);
        }
    }
    __shared__ float4 red[4][64];
    red[grp][ps] = make_float4(t0, t1, t2, t3);
    __syncthreads();

    if (tid < 64) {
        float4 a = red[0][ps], b = red[1][ps], c = red[2][ps], d = red[3][ps];
        float v0 = (a.x + b.x + c.x + d.x) * 0.0625f;
        float v1 = (a.y + b.y + c.y + d.y) * 0.0625f;
        float v2 = (a.z + b.z + c.z + d.z) * 0.0625f;
        float v3 = (a.w + b.w + c.w + d.w) * 0.0625f;
        // inner = w*256 + l*4 + np ; l = em + 16*q ; u2 covers e 4q..4q+3
        const int ww = inner >> 8, l = (inner >> 2) & 63, np = inner & 3;
        const int em = l & 15, qq = l >> 4;
        const int bg = bt * 16 + em, nn = 4 * ww + np;
        float2* ap = acc + (size_t)bg * 128 + nn * 8 + 2 * qq;
        ap[0] = make_float2(v0, v1);
        ap[1] = make_float2(v2, v3);
    }
}

// ---- routing passes 1/2: pure consumers of hat. 2-chunk double-buffered
// prefetch (16 uint2 live = 32 VGPR, fits the (256,4) cap without spill).
// softmax over n via 16-lane DPP rows; write partial[ic][b][n][e] (consumer
// order). MODE 1: pr = squash(accA+B).  MODE 2: pr = sq(accA+B)+sq(accB+B). ----
template<int MODE>
__global__ __launch_bounds__(256, 4)
void caps_pass_r(const unsigned short* __restrict__ hat, const float* __restrict__ Bb,
                 const float* __restrict__ accA, const float* __restrict__ accB,
                 unsigned short* __restrict__ partial)
{
    const int tid  = threadIdx.x;
    const int lane = tid & 63;
    const int w    = tid >> 6;
    const int n    = lane & 15;
    const int q    = lane >> 4;
    int ic, bt; decode_blk(blockIdx.x, ic, bt);
    const int b_loc = 4 * w + q;
    const int b_glb = bt * 16 + b_loc;

    // ---- prologue: pr[e] for this thread's (b_glb, n) ----
    float pr[16];
    {
        const float4* bbp = (const float4*)(Bb + (n << 4));
        const float4* ap  = (const float4*)(accA + ((size_t)b_glb << 8) + (n << 4));
        float s[16], s2 = 0.f;
        #pragma unroll
        for (int k4 = 0; k4 < 4; ++k4) {
            float4 a = ap[k4], bb = bbp[k4];
            s[4*k4+0] = a.x + bb.x; s[4*k4+1] = a.y + bb.y;
            s[4*k4+2] = a.z + bb.z; s[4*k4+3] = a.w + bb.w;
        }
        #pragma unroll
        for (int e = 0; e < 16; ++e) s2 = fmaf(s[e], s[e], s2);
        float sc = sqrtf(s2) / (1.0f + s2);
        #pragma unroll
        for (int e = 0; e < 16; ++e) pr[e] = s[e] * sc;
        if (MODE == 2) {
            const float4* ap2 = (const float4*)(accB + ((size_t)b_glb << 8) + (n << 4));
            float t[16], t2 = 0.f;
            #pragma unroll
            for (int k4 = 0; k4 < 4; ++k4) {
                float4 a = ap2[k4], bb = bbp[k4];
                t[4*k4+0] = a.x + bb.x; t[4*k4+1] = a.y + bb.y;
                t[4*k4+2] = a.z + bb.z; t[4*k4+3] = a.w + bb.w;
            }
            #pragma unroll
            for (int e = 0; e < 16; ++e) t2 = fmaf(t[e], t[e], t2);
            float sc2 = sqrtf(t2) / (1.0f + t2);
            #pragma unroll
            for (int e = 0; e < 16; ++e) pr[e] = fmaf(t[e], sc2, pr[e]);
        }
    }

    // hat u2 idx (producer coords): (n>>2)*256 + (eq*16 + b_loc)*4 + (n&3)
    const uint2* hq = (const uint2*)hat + (size_t)(ic * 8 + bt) * HAT_BLK_U2
                    + (size_t)(n >> 2) * 256 + b_loc * 4 + (n & 3);

    float acc[16];
    #pragma unroll
    for (int e = 0; e < 16; ++e) acc[e] = 0.f;

    uint2 hu[2][8];
    // prime: batch 0 = chunks 0,1
    #pragma unroll
    for (int c2 = 0; c2 < 2; ++c2)
        #pragma unroll
        for (int eq = 0; eq < 4; ++eq)
            hu[0][c2 * 4 + eq] = hq[(size_t)c2 * 1024 + eq * 64];

    #pragma unroll
    for (int bb = 0; bb < 4; ++bb) {
        if (bb < 3) {   // prefetch next batch into the other buffer
            #pragma unroll
            for (int c2 = 0; c2 < 2; ++c2)
                #pragma unroll
                for (int eq = 0; eq < 4; ++eq)
                    hu[(bb + 1) & 1][c2 * 4 + eq] =
                        hq[(size_t)((bb + 1) * 2 + c2) * 1024 + eq * 64];
        }
        #pragma unroll
        for (int c2 = 0; c2 < 2; ++c2) {
            float h[16];
            {
                unsigned uu[8];
                #pragma unroll
                for (int eq = 0; eq < 4; ++eq) {
                    uu[2*eq]   = hu[bb & 1][c2 * 4 + eq].x;
                    uu[2*eq+1] = hu[bb & 1][c2 * 4 + eq].y;
                }
                #pragma unroll
                for (int jj = 0; jj < 8; ++jj) {
                    h[2*jj]   = __uint_as_float(uu[jj] << 16);
                    h[2*jj+1] = __uint_as_float(uu[jj] & 0xFFFF0000u);
                }
            }
            float lg = 0.f;
            #pragma unroll
            for (int e = 0; e < 16; ++e) lg = fmaf(pr[e], h[e], lg);
            float p = __expf(lg);                 // |lg| small -> max-free
            float z = dpp_sum16(p);               // softmax over n = 16-lane DPP row
            float c = p * __builtin_amdgcn_rcpf(z);
            #pragma unroll
            for (int e = 0; e < 16; ++e) acc[e] = fmaf(c, h[e], acc[e]);
        }
    }

    // ---- epilogue: bf16 partial[ic][b][n][e] (consumer order) ----
    unsigned short* pp = partial + (((size_t)ic * B_SZ + b_glb) << 8) + (n << 4);
    uint4 o0 = {pk2(acc[0], acc[1]),   pk2(acc[2], acc[3]),
                pk2(acc[4], acc[5]),   pk2(acc[6], acc[7])};
    uint4 o1 = {pk2(acc[8], acc[9]),   pk2(acc[10], acc[11]),
                pk2(acc[12], acc[13]), pk2(acc[14], acc[15])};
    *(uint4*)pp = o0;
    *(uint4*)(pp + 8) = o1;
}

// ---- reduce 144 bf16 slices (consumer order). MODE 1: acc write.
// MODE 2: FINAL adds B + squash (8-lane DPP). ----
template<int MODE>
__global__ __launch_bounds__(256)
void caps_reduce(const unsigned* __restrict__ partial, const float* __restrict__ Bb,
                 float2* __restrict__ acc, float2* __restrict__ out)
{
    const int tid = threadIdx.x;
    const int ps  = tid & 63;
    const int grp = tid >> 6;
    const int pos = blockIdx.x * 64 + ps;        // uint index in [0, 16384)

    float t0 = 0.f, t1 = 0.f;
    #pragma unroll 6
    for (int k = 0; k < ICN / 4; ++k) {
        unsigned u = partial[(size_t)(grp * (ICN / 4) + k) * (OUT_ELEMS / 2) + pos];
        t0 += __uint_as_float(u << 16);
        t1 += __uint_as_float(u & 0xFFFF0000u);
    }
    __shared__ float2 red[4][64];
    red[grp][ps] = make_float2(t0, t1);
    __syncthreads();

    if (tid < 64) {
        float2 a = red[0][ps], b = red[1][ps], c = red[2][ps], d = red[3][ps];
        float v0 = a.x + b.x + c.x + d.x;
        float v1 = a.y + b.y + c.y + d.y;
        if (MODE == 1) {
            acc[pos] = make_float2(v0, v1);
        } else {
            const int n = (pos >> 3) & 15, ep = pos & 7;
            float2 bb = *(const float2*)(Bb + n * 16 + 2 * ep);
            v0 += bb.x; v1 += bb.y;
            float s2 = dpp_sum8(v0 * v0 + v1 * v1);   // e-row = 8 consecutive lanes
            float sc = sqrtf(s2) / (1.0f + s2);
            out[pos] = make_float2(v0 * sc, v1 * sc);
        }
    }
}

extern "C" void kernel_launch(void* const* d_in, const int* in_sizes, int n_in,
                              void* d_out, int out_size, void* d_ws, size_t ws_size,
                              hipStream_t stream)
{
    const float* x  = (const float*)d_in[0];   // [128,1152,8]
    const float* W  = (const float*)d_in[1];   // [16,1152,16,8]
    const float* Bb = (const float*)d_in[2];   // [16,16]
    float2* out = (float2*)d_out;              // [128,16,16] fp32

    float* accA = (float*)d_ws;                                    // 128 KB
    float* accB = accA + OUT_ELEMS;                                // 128 KB
    unsigned short* partial = (unsigned short*)(accB + OUT_ELEMS); // 144 x 64 KB = 9.4 MB
    unsigned short* hat = partial + (size_t)ICN * OUT_ELEMS;       // 75.5 MB bf16

    hat_mat<<<9216, 256, 0, stream>>>(x, W, hat);
    reduce0<<<128, 256, 0, stream>>>((const uint2*)hat, (float2*)accA);
    caps_pass_r<1><<<1152, 256, 0, stream>>>(hat, Bb, accA, nullptr, partial);
    caps_reduce<1><<<256, 256, 0, stream>>>((const unsigned*)partial, Bb, (float2*)accB, nullptr);
    caps_pass_r<2><<<1152, 256, 0, stream>>>(hat, Bb, accA, accB, partial);
    caps_reduce<2><<<256, 256, 0, stream>>>((const unsigned*)partial, Bb, nullptr, out);
}

// Round 6
// 134.876 us; speedup vs baseline: 1.0187x; 1.0187x over previous
//
#include <hip/hip_runtime.h>
#include <hip/hip_bf16.h>

#define B_SZ 128
#define IN_CAPS 1152
#define N_CAPS 16
#define DIM 16

#define IPB 8                         // i's per pass_r block
#define ICN (IN_CAPS / IPB)           // 144 partial slices
#define OUT_ELEMS (B_SZ * N_CAPS * DIM)   // 32768

// hat global layout (CONSUMER order): [i][b][n][e16] bf16.
// Per-i slab = 128*16*16 shorts = 64 KB = 4096 uint4.
#define HAT_I_U4 4096

// hat_mat LDS slab: uint2 grid [b=16][n=16][q=4], b-stride 66 u2 (528 B,
// 16B-aligned, and 66*2 mod 32 = 4 -> write conflicts <= 2-way).
#define SLAB_U2 1056   // 16*66

typedef __attribute__((ext_vector_type(8))) short bf16x8;   // MFMA A/B frag
typedef __attribute__((ext_vector_type(4))) float f32x4;    // MFMA C/D frag

__device__ __forceinline__ unsigned short f2bf(float f) {   // RNE
    unsigned u = __float_as_uint(f);
    u = u + 0x7fffu + ((u >> 16) & 1u);
    return (unsigned short)(u >> 16);
}
__device__ __forceinline__ unsigned pk2(float lo, float hi) {
    return ((unsigned)f2bf(hi) << 16) | f2bf(lo);
}
__device__ __forceinline__ unsigned cvtpk(float lo, float hi) {   // HW packed cvt (RNE)
    union { __hip_bfloat162 h; unsigned u; } c;
    c.h = __float22bfloat162_rn(make_float2(lo, hi));
    return c.u;
}

// DPP sums (VALU pipe — no DS traffic)
__device__ __forceinline__ float dpp_sum16(float v) {
    v += __int_as_float(__builtin_amdgcn_update_dpp(0, __float_as_int(v), 0xB1, 0xF, 0xF, true));
    v += __int_as_float(__builtin_amdgcn_update_dpp(0, __float_as_int(v), 0x4E, 0xF, 0xF, true));
    v += __int_as_float(__builtin_amdgcn_update_dpp(0, __float_as_int(v), 0x124, 0xF, 0xF, true));
    v += __int_as_float(__builtin_amdgcn_update_dpp(0, __float_as_int(v), 0x128, 0xF, 0xF, true));
    return v;
}
__device__ __forceinline__ float dpp_sum8(float v) {
    v += __int_as_float(__builtin_amdgcn_update_dpp(0, __float_as_int(v), 0xB1, 0xF, 0xF, true));
    v += __int_as_float(__builtin_amdgcn_update_dpp(0, __float_as_int(v), 0x4E, 0xF, 0xF, true));
    v += __int_as_float(__builtin_amdgcn_update_dpp(0, __float_as_int(v), 0x141, 0xF, 0xF, true));
    return v;
}

// ---- hat materialization: ONE block per i (1152 blocks). W f32 slice for i
// is converted to bf16 once into registers and reused across all 8 bt tiles
// (W read exactly once chip-wide). D-frags go through a padded LDS slab to
// emerge in CONSUMER layout; each thread stores 32 B contiguous. ----
__global__ __launch_bounds__(256)
void hat_mat(const float* __restrict__ x, const float* __restrict__ W,
             unsigned short* __restrict__ hat)
{
    const int tid  = threadIdx.x;
    const int lane = tid & 63;
    const int w    = tid >> 6;
    const int em   = lane & 15;       // A row = e ; B col = b
    const int q    = lane >> 4;       // D rows = e = 4q+r ; B k-slice
    const int i    = blockIdx.x;

    __shared__ __align__(16) uint2 slab[4 * SLAB_U2];   // 33 KB

    // A-frags: W[nn][i][em][0..7] f32 -> bf16 once, held in regs
    bf16x8 av[4];
    #pragma unroll
    for (int np = 0; np < 4; ++np) {
        const int nn = 4 * w + np;
        const float4* wp = (const float4*)(W + (((size_t)nn * IN_CAPS + i) * DIM + em) * 8);
        float4 wa = wp[0], wb2 = wp[1];
        union { uint4 u; bf16x8 v; } ax;
        ax.u.x = cvtpk(wa.x, wa.y);   ax.u.y = cvtpk(wa.z, wa.w);
        ax.u.z = cvtpk(wb2.x, wb2.y); ax.u.w = cvtpk(wb2.z, wb2.w);
        av[np] = ax.v;
    }

    unsigned short* hb = hat + (size_t)i * (HAT_I_U4 * 8);   // shorts

    #pragma unroll
    for (int r = 0; r < 2; ++r) {
        if (r) __syncthreads();       // slabs free again after round-0 store
        #pragma unroll
        for (int s = 0; s < 4; ++s) {
            const int bt = 4 * r + s;
            // B operand: x[b=em][i][0..7] -> bf16, k>=8 zeroed (kills A garbage)
            uint4 xu = {0u, 0u, 0u, 0u};
            if (q == 0) {
                const float4* xp = (const float4*)(x + ((size_t)(bt * 16 + em) * IN_CAPS + i) * 8);
                float4 a = xp[0], c = xp[1];
                xu.x = cvtpk(a.x, a.y); xu.y = cvtpk(a.z, a.w);
                xu.z = cvtpk(c.x, c.y); xu.w = cvtpk(c.z, c.w);
            }
            union { uint4 u; bf16x8 v; } bx; bx.u = xu;
            #pragma unroll
            for (int np = 0; np < 4; ++np) {
                const int nn = 4 * w + np;
                f32x4 cz = {0.f, 0.f, 0.f, 0.f};
                f32x4 d = __builtin_amdgcn_mfma_f32_16x16x32_bf16(av[np], bx.v, cz, 0, 0, 0);
                // lane (em=b, q): e = 4q..4q+3 for capsule nn
                slab[s * SLAB_U2 + em * 66 + nn * 4 + q] =
                    (uint2){cvtpk(d[0], d[1]), cvtpk(d[2], d[3])};
            }
        }
        __syncthreads();
        // store phase: thread (bl = tid>>4, n = tid&15) owns a (b,n) e-row
        const int bl = tid >> 4, n = tid & 15;
        #pragma unroll
        for (int s = 0; s < 4; ++s) {
            const int bt = 4 * r + s;
            const uint2* rp = &slab[s * SLAB_U2 + bl * 66 + n * 4];
            uint4 v0 = *(const uint4*)rp;        // e 0..7
            uint4 v1 = *(const uint4*)(rp + 2);  // e 8..15
            uint4* gp = (uint4*)hb + ((size_t)(bt * 16 + bl) * 16 + n) * 2;
            gp[0] = v0;                          // 32 B contiguous per thread,
            gp[1] = v1;                          // 512 B per 16 threads
        }
    }
}

// ---- reduce0: accA[b][n][e] = (1/16) * sum_i hat[i][b][n][e].
// 256 blocks x 256 thr: thread = (pos4 = blk*16 + tid&15, i-group = tid>>4
// of 72 i's); 16B loads, 256B contiguous per 16 lanes; LDS combine. ----
__global__ __launch_bounds__(256)
void reduce0(const uint4* __restrict__ hat4, float* __restrict__ acc)
{
    const int tid  = threadIdx.x;
    const int p    = tid & 15;
    const int g    = tid >> 4;
    const int pos4 = blockIdx.x * 16 + p;        // [0, 4096)
    const uint4* hp = hat4 + pos4;

    float t[8] = {0.f, 0.f, 0.f, 0.f, 0.f, 0.f, 0.f, 0.f};
    #pragma unroll 9
    for (int ii = g * 72; ii < g * 72 + 72; ++ii) {
        uint4 u = hp[(size_t)ii * HAT_I_U4];
        unsigned uu[4] = {u.x, u.y, u.z, u.w};
        #pragma unroll
        for (int k = 0; k < 4; ++k) {
            t[2*k]   += __uint_as_float(uu[k] << 16);
            t[2*k+1] += __uint_as_float(uu[k] & 0xFFFF0000u);
        }
    }
    __shared__ float red[16][16][10];   // [g][p][e pad] — p-stride 10 breaks banks
    #pragma unroll
    for (int e = 0; e < 8; ++e) red[g][p][e] = t[e];
    __syncthreads();

    if (tid < 128) {
        const int pp = tid >> 3, e = tid & 7;
        float v = 0.f;
        #pragma unroll
        for (int gg = 0; gg < 16; ++gg) v += red[gg][pp][e];
        v *= 0.0625f;
        const int pos = blockIdx.x * 16 + pp;
        const int b = pos >> 5, nn = (pos >> 1) & 15, half = pos & 1;
        acc[((size_t)b << 8) + (nn << 4) + half * 8 + e] = v;
    }
}

// ---- routing passes 1/2: pure consumers of hat (consumer layout). 16 x
// uint4 loads/thread (32 B contiguous per (b,n) row). Softmax over n via
// 16-lane DPP; write partial[ic][b][n][e] bf16.
// MODE 1: pr = squash(accA+B).  MODE 2: pr = sq(accA+B)+sq(accB+B). ----
template<int MODE>
__global__ __launch_bounds__(256, 4)
void caps_pass_r(const unsigned short* __restrict__ hat, const float* __restrict__ Bb,
                 const float* __restrict__ accA, const float* __restrict__ accB,
                 unsigned short* __restrict__ partial)
{
    const int tid  = threadIdx.x;
    const int lane = tid & 63;
    const int w    = tid >> 6;
    const int n    = lane & 15;
    const int q    = lane >> 4;
    const int bt   = blockIdx.x & 7;
    const int ic   = blockIdx.x >> 3;
    const int b_loc = 4 * w + q;
    const int b_glb = bt * 16 + b_loc;

    // ---- prologue: pr[e] for this thread's (b_glb, n) ----
    float pr[16];
    {
        const float4* bbp = (const float4*)(Bb + (n << 4));
        const float4* ap  = (const float4*)(accA + ((size_t)b_glb << 8) + (n << 4));
        float s[16], s2 = 0.f;
        #pragma unroll
        for (int k4 = 0; k4 < 4; ++k4) {
            float4 a = ap[k4], bb = bbp[k4];
            s[4*k4+0] = a.x + bb.x; s[4*k4+1] = a.y + bb.y;
            s[4*k4+2] = a.z + bb.z; s[4*k4+3] = a.w + bb.w;
        }
        #pragma unroll
        for (int e = 0; e < 16; ++e) s2 = fmaf(s[e], s[e], s2);
        float sc = sqrtf(s2) / (1.0f + s2);
        #pragma unroll
        for (int e = 0; e < 16; ++e) pr[e] = s[e] * sc;
        if (MODE == 2) {
            const float4* ap2 = (const float4*)(accB + ((size_t)b_glb << 8) + (n << 4));
            float t[16], t2 = 0.f;
            #pragma unroll
            for (int k4 = 0; k4 < 4; ++k4) {
                float4 a = ap2[k4], bb = bbp[k4];
                t[4*k4+0] = a.x + bb.x; t[4*k4+1] = a.y + bb.y;
                t[4*k4+2] = a.z + bb.z; t[4*k4+3] = a.w + bb.w;
            }
            #pragma unroll
            for (int e = 0; e < 16; ++e) t2 = fmaf(t[e], t[e], t2);
            float sc2 = sqrtf(t2) / (1.0f + t2);
            #pragma unroll
            for (int e = 0; e < 16; ++e) pr[e] = fmaf(t[e], sc2, pr[e]);
        }
    }

    // ---- prefetch hat panel: 16 x uint4, per chunk 32 B contiguous ----
    const uint4* hq = (const uint4*)hat + (size_t)(ic * IPB) * HAT_I_U4
                    + ((size_t)b_glb * 16 + n) * 2;
    uint4 hu[16];
    #pragma unroll
    for (int ch = 0; ch < IPB; ++ch) {
        hu[2*ch]   = hq[(size_t)ch * HAT_I_U4];
        hu[2*ch+1] = hq[(size_t)ch * HAT_I_U4 + 1];
    }

    float acc[16];
    #pragma unroll
    for (int e = 0; e < 16; ++e) acc[e] = 0.f;

    #pragma unroll
    for (int ch = 0; ch < IPB; ++ch) {
        float h[16];
        {
            uint4 u0 = hu[2*ch], u1 = hu[2*ch+1];
            unsigned uu[8] = {u0.x, u0.y, u0.z, u0.w, u1.x, u1.y, u1.z, u1.w};
            #pragma unroll
            for (int j = 0; j < 8; ++j) {
                h[2*j]   = __uint_as_float(uu[j] << 16);
                h[2*j+1] = __uint_as_float(uu[j] & 0xFFFF0000u);
            }
        }
        float lg = 0.f;
        #pragma unroll
        for (int e = 0; e < 16; ++e) lg = fmaf(pr[e], h[e], lg);
        float p = __expf(lg);                 // |lg| small -> max-free (R7-R9 proven)
        float z = dpp_sum16(p);               // softmax over n = 16-lane DPP row
        float c = p * __builtin_amdgcn_rcpf(z);
        #pragma unroll
        for (int e = 0; e < 16; ++e) acc[e] = fmaf(c, h[e], acc[e]);
    }

    // ---- epilogue: bf16 partial[ic][b][n][e] (thread owns the row) ----
    unsigned short* pp = partial + (((size_t)ic * B_SZ + b_glb) << 8) + (n << 4);
    uint4 o0 = {pk2(acc[0], acc[1]),   pk2(acc[2], acc[3]),
                pk2(acc[4], acc[5]),   pk2(acc[6], acc[7])};
    uint4 o1 = {pk2(acc[8], acc[9]),   pk2(acc[10], acc[11]),
                pk2(acc[12], acc[13]), pk2(acc[14], acc[15])};
    *(uint4*)pp = o0;
    *(uint4*)(pp + 8) = o1;
}

// ---- reduce 144 bf16 slices (consumer order). MODE 1: acc write.
// MODE 2: FINAL adds B + squash (8-lane DPP). ----
template<int MODE>
__global__ __launch_bounds__(256)
void caps_reduce(const unsigned* __restrict__ partial, const float* __restrict__ Bb,
                 float2* __restrict__ acc, float2* __restrict__ out)
{
    const int tid = threadIdx.x;
    const int ps  = tid & 63;
    const int grp = tid >> 6;
    const int pos = blockIdx.x * 64 + ps;        // uint index in [0, 16384)

    float t0 = 0.f, t1 = 0.f;
    #pragma unroll 6
    for (int k = 0; k < ICN / 4; ++k) {
        unsigned u = partial[(size_t)(grp * (ICN / 4) + k) * (OUT_ELEMS / 2) + pos];
        t0 += __uint_as_float(u << 16);
        t1 += __uint_as_float(u & 0xFFFF0000u);
    }
    __shared__ float2 red[4][64];
    red[grp][ps] = make_float2(t0, t1);
    __syncthreads();

    if (tid < 64) {
        float2 a = red[0][ps], b = red[1][ps], c = red[2][ps], d = red[3][ps];
        float v0 = a.x + b.x + c.x + d.x;
        float v1 = a.y + b.y + c.y + d.y;
        if (MODE == 1) {
            acc[pos] = make_float2(v0, v1);
        } else {
            const int n = (pos >> 3) & 15, ep = pos & 7;
            float2 bb = *(const float2*)(Bb + n * 16 + 2 * ep);
            v0 += bb.x; v1 += bb.y;
            float s2 = dpp_sum8(v0 * v0 + v1 * v1);   // e-row = 8 consecutive lanes
            float sc = sqrtf(s2) / (1.0f + s2);
            out[pos] = make_float2(v0 * sc, v1 * sc);
        }
    }
}

extern "C" void kernel_launch(void* const* d_in, const int* in_sizes, int n_in,
                              void* d_out, int out_size, void* d_ws, size_t ws_size,
                              hipStream_t stream)
{
    const float* x  = (const float*)d_in[0];   // [128,1152,8]
    const float* W  = (const float*)d_in[1];   // [16,1152,16,8]
    const float* Bb = (const float*)d_in[2];   // [16,16]
    float2* out = (float2*)d_out;              // [128,16,16] fp32

    float* accA = (float*)d_ws;                                    // 128 KB
    float* accB = accA + OUT_ELEMS;                                // 128 KB
    unsigned short* partial = (unsigned short*)(accB + OUT_ELEMS); // 144 x 64 KB = 9.4 MB
    unsigned short* hat = partial + (size_t)ICN * OUT_ELEMS;       // 75.5 MB bf16

    hat_mat<<<1152, 256, 0, stream>>>(x, W, hat);
    reduce0<<<256, 256, 0, stream>>>((const uint4*)hat, accA);
    caps_pass_r<1><<<1152, 256, 0, stream>>>(hat, Bb, accA, nullptr, partial);
    caps_reduce<1><<<256, 256, 0, stream>>>((const unsigned*)partial, Bb, (float2*)accB, nullptr);
    caps_pass_r<2><<<1152, 256, 0, stream>>>(hat, Bb, accA, accB, partial);
    caps_reduce<2><<<256, 256, 0, stream>>>((const unsigned*)partial, Bb, nullptr, out);
}